// Round 12
// baseline (718.921 us; speedup 1.0000x reference)
//
#include <hip/hip_runtime.h>

#define N_NODES 50000
#define N_EDGES 800000
#define LN_EPS 1e-5f
#define NBLK 196  // ceil(N_NODES/256)

typedef __attribute__((ext_vector_type(8))) short bf16x8;
typedef __attribute__((ext_vector_type(8))) unsigned short u16x8;
typedef __attribute__((ext_vector_type(4))) float f32x4;

static __device__ inline unsigned short f2bf(float f) {
  unsigned u = __float_as_uint(f);
  unsigned r = ((u >> 16) & 1) + 0x7fffu;
  return (unsigned short)((u + r) >> 16);
}
static __device__ inline float bf2f(unsigned short u) {
  return __uint_as_float((unsigned)u << 16);
}

// Fragment n-index -> true channel permutation: p(n) = (n&15)*4 + (n>>4).
// Lane (lr,tn) owns true channels lr*4+tn (contiguous), so bf16 node-feature
// buffers stay LINEAR; MFMA D rows are lg*4+j.

// ---- combined edge transforms: WcT[L][n][k] = (We@eW)[k][p(n)] bf16, bcC[L][n] = bias[p(n)] ----
__global__ void wcomb_kernel(const float* __restrict__ We, const float* __restrict__ be,
                             const float* __restrict__ eW0, const float* __restrict__ eb0,
                             const float* __restrict__ eW1, const float* __restrict__ eb1,
                             const float* __restrict__ eW2, const float* __restrict__ eb2,
                             unsigned short* __restrict__ WcT, float* __restrict__ bcC) {
  int L = blockIdx.x;
  const float* eW = L == 0 ? eW0 : (L == 1 ? eW1 : eW2);
  const float* eb = L == 0 ? eb0 : (L == 1 ? eb1 : eb2);
  int tid = threadIdx.x;
  for (int idx = tid; idx < 64 * 64; idx += 256) {
    int k = idx >> 6, n = idx & 63;
    int ch = (n & 15) * 4 + (n >> 4);  // p(n)
    float s = 0.f;
    for (int j = 0; j < 64; ++j) s = fmaf(We[k * 64 + j], eW[j * 64 + ch], s);
    WcT[L * 4096 + n * 64 + k] = f2bf(s);
  }
  if (tid < 64) {
    int ch = (tid & 15) * 4 + (tid >> 4);  // p(n)
    float s = eb[ch];
    for (int j = 0; j < 64; ++j) s = fmaf(be[j], eW[j * 64 + ch], s);
    bcC[L * 64 + tid] = s;
  }
}

// ---- node weight prep: WT[n][k] = W[k][p(n)] bf16, bP[n] = b[p(n)] ----
__global__ void wnode_kernel(const float* __restrict__ W0, const float* __restrict__ b0,
                             const float* __restrict__ W1, const float* __restrict__ b1,
                             const float* __restrict__ W2, const float* __restrict__ b2,
                             unsigned short* __restrict__ W0T, unsigned short* __restrict__ W1T,
                             unsigned short* __restrict__ W2T, float* __restrict__ bP) {
  int L = blockIdx.x;
  const float* W = L == 0 ? W0 : (L == 1 ? W1 : W2);
  const float* b = L == 0 ? b0 : (L == 1 ? b1 : b2);
  unsigned short* WT = L == 0 ? W0T : (L == 1 ? W1T : W2T);
  const int K = L == 0 ? 128 : 64;
  int tid = threadIdx.x;
  for (int idx = tid; idx < 64 * K; idx += 256) {
    int n = idx / K, k = idx % K;
    int ch = (n & 15) * 4 + (n >> 4);
    WT[idx] = f2bf(W[k * 64 + ch]);
  }
  if (tid < 64) {
    int ch = (tid & 15) * 4 + (tid >> 4);
    bP[L * 64 + tid] = b[ch];
  }
}

// ---- CSC build ----
__global__ void hist_kernel(const int* __restrict__ col, int* __restrict__ deg) {
  int e = blockIdx.x * blockDim.x + threadIdx.x;
  if (e < N_EDGES) atomicAdd(&deg[col[e]], 1);
}

__global__ __launch_bounds__(256) void scan1_kernel(const int* __restrict__ deg,
                                                    int* __restrict__ off, int* __restrict__ bsum) {
  __shared__ int s[256];
  int tid = threadIdx.x, i = blockIdx.x * 256 + tid;
  int v = (i < N_NODES) ? deg[i] : 0;
  s[tid] = v;
  __syncthreads();
  for (int d = 1; d < 256; d <<= 1) {
    int t = (tid >= d) ? s[tid - d] : 0;
    __syncthreads();
    s[tid] += t;
    __syncthreads();
  }
  if (i < N_NODES) off[i] = s[tid] - v;
  if (tid == 255) bsum[blockIdx.x] = s[255];
}

__global__ __launch_bounds__(256) void scan2_kernel(int* __restrict__ bsum) {
  __shared__ int s[256];
  int tid = threadIdx.x;
  int v = (tid < NBLK) ? bsum[tid] : 0;
  s[tid] = v;
  __syncthreads();
  for (int d = 1; d < 256; d <<= 1) {
    int t = (tid >= d) ? s[tid - d] : 0;
    __syncthreads();
    s[tid] += t;
    __syncthreads();
  }
  if (tid < NBLK) bsum[tid] = s[tid] - v;
}

// scan finalize + cursor init + dis + packed {off,deg}
__global__ void scan3_kernel(int* __restrict__ off, const int* __restrict__ bsum,
                             int* __restrict__ cursor, const int* __restrict__ deg,
                             float* __restrict__ dis, int2* __restrict__ od) {
  int i = blockIdx.x * 256 + threadIdx.x;
  if (i < N_NODES) {
    int o = off[i] + bsum[blockIdx.x];
    off[i] = o;
    cursor[i] = o;
    int d = deg[i];
    dis[i] = d > 0 ? rsqrtf((float)d) : 0.f;
    int2 p; p.x = o; p.y = d;
    od[i] = p;
  }
}

// CSC scatter: perm + packed meta {row, nrm}
__global__ void scatter2_kernel(const int* __restrict__ rowI, const int* __restrict__ colI,
                                const float* __restrict__ dis, int* __restrict__ cursor,
                                int* __restrict__ perm, int2* __restrict__ metaP) {
  int e = blockIdx.x * blockDim.x + threadIdx.x;
  if (e < N_EDGES) {
    int c = colI[e], r = rowI[e];
    int p = atomicAdd(&cursor[c], 1);
    perm[p] = e;
    int2 m;
    m.x = r;
    m.y = __float_as_int(dis[r] * dis[c]);
    metaP[p] = m;
  }
}

// permute attr rows into CSC order, f32 -> bf16; 8 threads/row, 32B read / 16B write
__global__ void permA_kernel(const float* __restrict__ attr, const int* __restrict__ perm,
                             unsigned short* __restrict__ attrP) {
  int t = blockIdx.x * 256 + threadIdx.x;  // E*8 threads, 8 channels each
  int i = t >> 3, q = t & 7;
  if (i >= N_EDGES) return;
  int e = perm[i];
  float4 v0 = *(const float4*)(attr + (size_t)e * 64 + q * 8);
  float4 v1 = *(const float4*)(attr + (size_t)e * 64 + q * 8 + 4);
  u16x8 o;
  o[0] = f2bf(v0.x); o[1] = f2bf(v0.y); o[2] = f2bf(v0.z); o[3] = f2bf(v0.w);
  o[4] = f2bf(v1.x); o[5] = f2bf(v1.y); o[6] = f2bf(v1.z); o[7] = f2bf(v1.w);
  *(u16x8*)(attrP + (size_t)i * 64 + q * 8) = o;
}

// ---- MFMA node GEMM K=128 (layer 0): wave = 16 rows; bf16 out LINEAR ----
__global__ __launch_bounds__(256, 3) void node_mfma128_kernel(
    const float* __restrict__ X, const unsigned short* __restrict__ WT,
    const float* __restrict__ bP, unsigned short* __restrict__ Y) {
  const int lane = threadIdx.x & 63;
  const int lr = lane & 15, lg = lane >> 4;
  const int wt = (blockIdx.x * 256 + threadIdx.x) >> 6;
  if (wt * 16 >= N_NODES) return;
  const int rowbase = wt * 16;

  bf16x8 bfrag[4][4];
  float bias[4];
#pragma unroll
  for (int tn = 0; tn < 4; ++tn) {
    bias[tn] = bP[tn * 16 + lr];
#pragma unroll
    for (int ks = 0; ks < 4; ++ks)
      bfrag[tn][ks] = *(const bf16x8*)(WT + (tn * 16 + lr) * 128 + ks * 32 + lg * 8);
  }
  const float* xr = X + (size_t)(rowbase + lr) * 128;
  bf16x8 af[4];
#pragma unroll
  for (int ks = 0; ks < 4; ++ks) {
    float4 a = *(const float4*)(xr + ks * 32 + lg * 8);
    float4 b = *(const float4*)(xr + ks * 32 + lg * 8 + 4);
    bf16x8 f;
    f[0] = (short)f2bf(a.x); f[1] = (short)f2bf(a.y);
    f[2] = (short)f2bf(a.z); f[3] = (short)f2bf(a.w);
    f[4] = (short)f2bf(b.x); f[5] = (short)f2bf(b.y);
    f[6] = (short)f2bf(b.z); f[7] = (short)f2bf(b.w);
    af[ks] = f;
  }
  f32x4 acc[4];
#pragma unroll
  for (int tn = 0; tn < 4; ++tn) {
    f32x4 z = {bias[tn], bias[tn], bias[tn], bias[tn]};
#pragma unroll
    for (int ks = 0; ks < 4; ++ks)
      z = __builtin_amdgcn_mfma_f32_16x16x32_bf16(af[ks], bfrag[tn][ks], z, 0, 0, 0);
    acc[tn] = z;
  }
#pragma unroll
  for (int j = 0; j < 4; ++j) {
    ushort4 o = {f2bf(acc[0][j]), f2bf(acc[1][j]), f2bf(acc[2][j]), f2bf(acc[3][j])};
    *(ushort4*)(Y + (size_t)(rowbase + lg * 4 + j) * 64 + lr * 4) = o;
  }
}

// ---- MFMA node GEMM K=64 with fused input ReLU+LayerNorm ----
__global__ __launch_bounds__(256, 3) void node_mfma64_kernel(
    const float* __restrict__ X, const unsigned short* __restrict__ WT,
    const float* __restrict__ bP, const float* __restrict__ G,
    const float* __restrict__ BT, unsigned short* __restrict__ Y) {
  const int lane = threadIdx.x & 63;
  const int lr = lane & 15, lg = lane >> 4;
  const int wt = (blockIdx.x * 256 + threadIdx.x) >> 6;
  if (wt * 16 >= N_NODES) return;
  const int rowbase = wt * 16;

  bf16x8 bfrag[4][2];
  float bias[4];
#pragma unroll
  for (int tn = 0; tn < 4; ++tn) {
    bias[tn] = bP[tn * 16 + lr];
#pragma unroll
    for (int ks = 0; ks < 2; ++ks)
      bfrag[tn][ks] = *(const bf16x8*)(WT + (tn * 16 + lr) * 64 + ks * 32 + lg * 8);
  }
  const float* xr = X + (size_t)(rowbase + lr) * 64;
  float v[16];
#pragma unroll
  for (int ks = 0; ks < 2; ++ks) {
    float4 a = *(const float4*)(xr + ks * 32 + lg * 8);
    float4 b = *(const float4*)(xr + ks * 32 + lg * 8 + 4);
    v[ks * 8 + 0] = a.x; v[ks * 8 + 1] = a.y; v[ks * 8 + 2] = a.z; v[ks * 8 + 3] = a.w;
    v[ks * 8 + 4] = b.x; v[ks * 8 + 5] = b.y; v[ks * 8 + 6] = b.z; v[ks * 8 + 7] = b.w;
  }
  float s = 0.f;
#pragma unroll
  for (int i = 0; i < 16; ++i) { v[i] = fmaxf(v[i], 0.f); s += v[i]; }
  s += __shfl_xor(s, 16); s += __shfl_xor(s, 32);
  float mu = s * (1.f / 64.f);
  float q = 0.f;
#pragma unroll
  for (int i = 0; i < 16; ++i) { float d = v[i] - mu; q += d * d; }
  q += __shfl_xor(q, 16); q += __shfl_xor(q, 32);
  float is = rsqrtf(q * (1.f / 64.f) + LN_EPS);
  bf16x8 af[2];
#pragma unroll
  for (int ks = 0; ks < 2; ++ks) {
    const float* gp = G + ks * 32 + lg * 8;
    const float* bp = BT + ks * 32 + lg * 8;
    float4 g0 = *(const float4*)(gp), g1 = *(const float4*)(gp + 4);
    float4 t0 = *(const float4*)(bp), t1 = *(const float4*)(bp + 4);
    float gg[8] = {g0.x, g0.y, g0.z, g0.w, g1.x, g1.y, g1.z, g1.w};
    float tt[8] = {t0.x, t0.y, t0.z, t0.w, t1.x, t1.y, t1.z, t1.w};
    bf16x8 f;
#pragma unroll
    for (int i = 0; i < 8; ++i)
      f[i] = (short)f2bf((v[ks * 8 + i] - mu) * is * gg[i] + tt[i]);
    af[ks] = f;
  }
  f32x4 acc[4];
#pragma unroll
  for (int tn = 0; tn < 4; ++tn) {
    f32x4 z = {bias[tn], bias[tn], bias[tn], bias[tn]};
    z = __builtin_amdgcn_mfma_f32_16x16x32_bf16(af[0], bfrag[tn][0], z, 0, 0, 0);
    z = __builtin_amdgcn_mfma_f32_16x16x32_bf16(af[1], bfrag[tn][1], z, 0, 0, 0);
    acc[tn] = z;
  }
#pragma unroll
  for (int j = 0; j < 4; ++j) {
    ushort4 o = {f2bf(acc[0][j]), f2bf(acc[1][j]), f2bf(acc[2][j]), f2bf(acc[3][j])};
    *(ushort4*)(Y + (size_t)(rowbase + lg * 4 + j) * 64 + lr * 4) = o;
  }
}

// ---- per-destination fused edge GEMM + aggregation: 2 cols per wave,
//      interleaved chains; scalarized accumulator; (256,4) occupancy ----
__global__ __launch_bounds__(256, 4) void edge_agg_kernel(
    const unsigned short* __restrict__ attrP, const int2* __restrict__ metaP,
    const int2* __restrict__ od, const unsigned short* __restrict__ WcT,
    const float* __restrict__ bc, const unsigned short* __restrict__ XLb,
    float* __restrict__ OUT) {
  const int lane = threadIdx.x & 63;
  const int lr = lane & 15, lg = lane >> 4;
  const int gw = (blockIdx.x * 256 + threadIdx.x) >> 6;
  const int cA = gw * 2, cB = cA + 1;
  if (cA >= N_NODES) return;
  const bool hasB = cB < N_NODES;

  // start the longest chains first
  int2 oA = od[cA];
  int2 oB = hasB ? od[cB] : make_int2(0, 0);

  bf16x8 bfrag[4][2];
  float bias[4];
#pragma unroll
  for (int tn = 0; tn < 4; ++tn) {
    bias[tn] = bc[tn * 16 + lr];
#pragma unroll
    for (int kb = 0; kb < 2; ++kb)
      bfrag[tn][kb] = *(const bf16x8*)(WcT + (tn * 16 + lr) * 64 + kb * 32 + lg * 8);
  }

  const int nbA = (oA.y + 15) >> 4;
  const int nbB = (oB.y + 15) >> 4;
  const int nb = nbA > nbB ? nbA : nbB;
  const int lastA = oA.x + (oA.y > 0 ? oA.y - 1 : 0);
  const int lastB = oB.x + (oB.y > 0 ? oB.y - 1 : 0);
  float fsA[4] = {0.f, 0.f, 0.f, 0.f};
  float fsB[4] = {0.f, 0.f, 0.f, 0.f};

#pragma unroll 1
  for (int b = 0; b < nb; ++b) {
    const int base = b * 16;
    const bool actA = b < nbA, actB = b < nbB;  // wave-uniform
    bf16x8 a0A, a1A, a0B, a1B;
    float nmA[4], nmB[4];
    int rjA[4], rjB[4];
    ushort4 xqA[4], xqB[4];
    if (actA) {
      int ea = min(oA.x + base + lr, lastA);
      const unsigned short* ap = attrP + (size_t)ea * 64 + lg * 8;
      a0A = *(const bf16x8*)(ap);
      a1A = *(const bf16x8*)(ap + 32);
#pragma unroll
      for (int j = 0; j < 4; ++j) {
        int idx = base + lg * 4 + j;
        int2 m = metaP[min(oA.x + idx, lastA)];
        rjA[j] = m.x;
        nmA[j] = (idx < oA.y) ? __int_as_float(m.y) : 0.f;
      }
    }
    if (actB) {
      int ea = min(oB.x + base + lr, lastB);
      const unsigned short* ap = attrP + (size_t)ea * 64 + lg * 8;
      a0B = *(const bf16x8*)(ap);
      a1B = *(const bf16x8*)(ap + 32);
#pragma unroll
      for (int j = 0; j < 4; ++j) {
        int idx = base + lg * 4 + j;
        int2 m = metaP[min(oB.x + idx, lastB)];
        rjB[j] = m.x;
        nmB[j] = (idx < oB.y) ? __int_as_float(m.y) : 0.f;
      }
    }
    if (actA) {
#pragma unroll
      for (int j = 0; j < 4; ++j)
        xqA[j] = *(const ushort4*)(XLb + (size_t)rjA[j] * 64 + lr * 4);
    }
    if (actB) {
#pragma unroll
      for (int j = 0; j < 4; ++j)
        xqB[j] = *(const ushort4*)(XLb + (size_t)rjB[j] * 64 + lr * 4);
    }
    if (actA) {
#pragma unroll
      for (int tn = 0; tn < 4; ++tn) {
        f32x4 z = {bias[tn], bias[tn], bias[tn], bias[tn]};
        z = __builtin_amdgcn_mfma_f32_16x16x32_bf16(a0A, bfrag[tn][0], z, 0, 0, 0);
        z = __builtin_amdgcn_mfma_f32_16x16x32_bf16(a1A, bfrag[tn][1], z, 0, 0, 0);
        const unsigned short* xp = (const unsigned short*)&xqA[0];
        // xqA[j] lanes: channel tn at component tn
        fsA[tn] = fmaf(z[0] * nmA[0], bf2f(((const unsigned short*)&xqA[0])[tn]), fsA[tn]);
        fsA[tn] = fmaf(z[1] * nmA[1], bf2f(((const unsigned short*)&xqA[1])[tn]), fsA[tn]);
        fsA[tn] = fmaf(z[2] * nmA[2], bf2f(((const unsigned short*)&xqA[2])[tn]), fsA[tn]);
        fsA[tn] = fmaf(z[3] * nmA[3], bf2f(((const unsigned short*)&xqA[3])[tn]), fsA[tn]);
        (void)xp;
      }
    }
    if (actB) {
#pragma unroll
      for (int tn = 0; tn < 4; ++tn) {
        f32x4 z = {bias[tn], bias[tn], bias[tn], bias[tn]};
        z = __builtin_amdgcn_mfma_f32_16x16x32_bf16(a0B, bfrag[tn][0], z, 0, 0, 0);
        z = __builtin_amdgcn_mfma_f32_16x16x32_bf16(a1B, bfrag[tn][1], z, 0, 0, 0);
        fsB[tn] = fmaf(z[0] * nmB[0], bf2f(((const unsigned short*)&xqB[0])[tn]), fsB[tn]);
        fsB[tn] = fmaf(z[1] * nmB[1], bf2f(((const unsigned short*)&xqB[1])[tn]), fsB[tn]);
        fsB[tn] = fmaf(z[2] * nmB[2], bf2f(((const unsigned short*)&xqB[2])[tn]), fsB[tn]);
        fsB[tn] = fmaf(z[3] * nmB[3], bf2f(((const unsigned short*)&xqB[3])[tn]), fsB[tn]);
      }
    }
  }
#pragma unroll
  for (int tn = 0; tn < 4; ++tn) {
    fsA[tn] += __shfl_xor(fsA[tn], 16);
    fsA[tn] += __shfl_xor(fsA[tn], 32);
    fsB[tn] += __shfl_xor(fsB[tn], 16);
    fsB[tn] += __shfl_xor(fsB[tn], 32);
  }
  if (lg == 0) {
    float4 oa = {fsA[0], fsA[1], fsA[2], fsA[3]};  // channels lr*4 .. lr*4+3
    *(float4*)(OUT + (size_t)cA * 64 + lr * 4) = oa;
    if (hasB) {
      float4 ob = {fsB[0], fsB[1], fsB[2], fsB[3]};
      *(float4*)(OUT + (size_t)cB * 64 + lr * 4) = ob;
    }
  }
}

extern "C" void kernel_launch(void* const* d_in, const int* in_sizes, int n_in,
                              void* d_out, int out_size, void* d_ws, size_t ws_size,
                              hipStream_t stream) {
  const float* x    = (const float*)d_in[0];
  const int* eidx   = (const int*)d_in[1];
  const float* attr = (const float*)d_in[2];
  const float* We  = (const float*)d_in[3];
  const float* be  = (const float*)d_in[4];
  const float* W0  = (const float*)d_in[5];  const float* b0  = (const float*)d_in[6];
  const float* eW0 = (const float*)d_in[7];  const float* eb0 = (const float*)d_in[8];
  const float* W1  = (const float*)d_in[9];  const float* b1  = (const float*)d_in[10];
  const float* eW1 = (const float*)d_in[11]; const float* eb1 = (const float*)d_in[12];
  const float* W2  = (const float*)d_in[13]; const float* b2  = (const float*)d_in[14];
  const float* eW2 = (const float*)d_in[15]; const float* eb2 = (const float*)d_in[16];
  const float* g0  = (const float*)d_in[17]; const float* bt0 = (const float*)d_in[18];
  const float* g1  = (const float*)d_in[19]; const float* bt1 = (const float*)d_in[20];
  const int* rowI = eidx;
  const int* colI = eidx + N_EDGES;

  char* base = (char*)d_ws;
  size_t pos = 0;
  auto alloc = [&](size_t b) -> char* {
    char* p = base + pos;
    pos += (b + 255) & ~(size_t)255;
    return p;
  };
  unsigned short* XLb = (unsigned short*)alloc((size_t)N_NODES * 64 * 2);
  float* hB   = (float*)alloc((size_t)N_NODES * 64 * 4);
  int2* metaP = (int2*)alloc((size_t)N_EDGES * 8);
  int* perm   = (int*)alloc((size_t)N_EDGES * 4);
  int* degI   = (int*)alloc((size_t)N_NODES * 4);
  float* disF = (float*)alloc((size_t)N_NODES * 4);
  int* offB   = (int*)alloc((size_t)N_NODES * 4);
  int* curB   = (int*)alloc((size_t)N_NODES * 4);
  int2* od    = (int2*)alloc((size_t)N_NODES * 8);
  int* bsum   = (int*)alloc(256 * 4);
  unsigned short* WcT = (unsigned short*)alloc(3 * 4096 * 2);
  float* bcC  = (float*)alloc(3 * 64 * 4);
  unsigned short* W0T = (unsigned short*)alloc(64 * 128 * 2);
  unsigned short* W1T = (unsigned short*)alloc(64 * 64 * 2);
  unsigned short* W2T = (unsigned short*)alloc(64 * 64 * 2);
  float* bPn  = (float*)alloc(3 * 64 * 4);
  unsigned short* attrP = (unsigned short*)alloc((size_t)N_EDGES * 64 * 2);
  (void)ws_size;
  float* out = (float*)d_out;

  // CSC build (sorted by destination col)
  hipMemsetAsync(degI, 0, (size_t)N_NODES * 4, stream);
  hist_kernel<<<N_EDGES / 256, 256, 0, stream>>>(colI, degI);
  scan1_kernel<<<NBLK, 256, 0, stream>>>(degI, offB, bsum);
  scan2_kernel<<<1, 256, 0, stream>>>(bsum);
  scan3_kernel<<<NBLK, 256, 0, stream>>>(offB, bsum, curB, degI, disF, od);
  scatter2_kernel<<<N_EDGES / 256, 256, 0, stream>>>(rowI, colI, disF, curB, perm, metaP);
  permA_kernel<<<(N_EDGES * 8) / 256, 256, 0, stream>>>(attr, perm, attrP);
  wcomb_kernel<<<3, 256, 0, stream>>>(We, be, eW0, eb0, eW1, eb1, eW2, eb2, WcT, bcC);
  wnode_kernel<<<3, 256, 0, stream>>>(W0, b0, W1, b1, W2, b2, W0T, W1T, W2T, bPn);

  const int node_grid = (N_NODES / 16 + 3) / 4;  // 16 rows/wave, 4 waves/block
  const int agg_grid = (N_NODES + 7) / 8;        // 2 cols/wave, 4 waves/block
  // layer 0
  node_mfma128_kernel<<<node_grid, 256, 0, stream>>>(x, W0T, bPn, XLb);
  edge_agg_kernel<<<agg_grid, 256, 0, stream>>>(attrP, metaP, od, WcT, bcC, XLb, hB);
  // layer 1 (input ReLU+LN fused)
  node_mfma64_kernel<<<node_grid, 256, 0, stream>>>(hB, W1T, bPn + 64, g0, bt0, XLb);
  edge_agg_kernel<<<agg_grid, 256, 0, stream>>>(attrP, metaP, od, WcT + 4096, bcC + 64, XLb, hB);
  // layer 2
  node_mfma64_kernel<<<node_grid, 256, 0, stream>>>(hB, W2T, bPn + 128, g1, bt1, XLb);
  edge_agg_kernel<<<agg_grid, 256, 0, stream>>>(attrP, metaP, od, WcT + 8192, bcC + 128, XLb, out);
}

// Round 13
// 459.788 us; speedup vs baseline: 1.5636x; 1.5636x over previous
//
#include <hip/hip_runtime.h>

#define N_NODES 50000
#define N_EDGES 800000
#define LN_EPS 1e-5f
#define NBLK 196  // ceil(N_NODES/256)

typedef __attribute__((ext_vector_type(8))) short bf16x8;
typedef __attribute__((ext_vector_type(8))) unsigned short u16x8;
typedef __attribute__((ext_vector_type(4))) float f32x4;

static __device__ inline unsigned short f2bf(float f) {
  unsigned u = __float_as_uint(f);
  unsigned r = ((u >> 16) & 1) + 0x7fffu;
  return (unsigned short)((u + r) >> 16);
}
static __device__ inline float bf2f(unsigned short u) {
  return __uint_as_float((unsigned)u << 16);
}

// Fragment n-index -> true channel permutation: p(n) = (n&15)*4 + (n>>4).
// Lane (lr,tn) owns true channels lr*4+tn (contiguous), so bf16 node-feature
// buffers stay LINEAR; MFMA D rows are lg*4+j.

// ---- combined edge transforms: WcT[L][n][k] = (We@eW)[k][p(n)] bf16, bcC[L][n] = bias[p(n)] ----
__global__ void wcomb_kernel(const float* __restrict__ We, const float* __restrict__ be,
                             const float* __restrict__ eW0, const float* __restrict__ eb0,
                             const float* __restrict__ eW1, const float* __restrict__ eb1,
                             const float* __restrict__ eW2, const float* __restrict__ eb2,
                             unsigned short* __restrict__ WcT, float* __restrict__ bcC) {
  int L = blockIdx.x;
  const float* eW = L == 0 ? eW0 : (L == 1 ? eW1 : eW2);
  const float* eb = L == 0 ? eb0 : (L == 1 ? eb1 : eb2);
  int tid = threadIdx.x;
  for (int idx = tid; idx < 64 * 64; idx += 256) {
    int k = idx >> 6, n = idx & 63;
    int ch = (n & 15) * 4 + (n >> 4);  // p(n)
    float s = 0.f;
    for (int j = 0; j < 64; ++j) s = fmaf(We[k * 64 + j], eW[j * 64 + ch], s);
    WcT[L * 4096 + n * 64 + k] = f2bf(s);
  }
  if (tid < 64) {
    int ch = (tid & 15) * 4 + (tid >> 4);  // p(n)
    float s = eb[ch];
    for (int j = 0; j < 64; ++j) s = fmaf(be[j], eW[j * 64 + ch], s);
    bcC[L * 64 + tid] = s;
  }
}

// ---- node weight prep: WT[n][k] = W[k][p(n)] bf16, bP[n] = b[p(n)] ----
__global__ void wnode_kernel(const float* __restrict__ W0, const float* __restrict__ b0,
                             const float* __restrict__ W1, const float* __restrict__ b1,
                             const float* __restrict__ W2, const float* __restrict__ b2,
                             unsigned short* __restrict__ W0T, unsigned short* __restrict__ W1T,
                             unsigned short* __restrict__ W2T, float* __restrict__ bP) {
  int L = blockIdx.x;
  const float* W = L == 0 ? W0 : (L == 1 ? W1 : W2);
  const float* b = L == 0 ? b0 : (L == 1 ? b1 : b2);
  unsigned short* WT = L == 0 ? W0T : (L == 1 ? W1T : W2T);
  const int K = L == 0 ? 128 : 64;
  int tid = threadIdx.x;
  for (int idx = tid; idx < 64 * K; idx += 256) {
    int n = idx / K, k = idx % K;
    int ch = (n & 15) * 4 + (n >> 4);
    WT[idx] = f2bf(W[k * 64 + ch]);
  }
  if (tid < 64) {
    int ch = (tid & 15) * 4 + (tid >> 4);
    bP[L * 64 + tid] = b[ch];
  }
}

// ---- CSC build ----
__global__ void hist_kernel(const int* __restrict__ col, int* __restrict__ deg) {
  int e = blockIdx.x * blockDim.x + threadIdx.x;
  if (e < N_EDGES) atomicAdd(&deg[col[e]], 1);
}

__global__ __launch_bounds__(256) void scan1_kernel(const int* __restrict__ deg,
                                                    int* __restrict__ off, int* __restrict__ bsum) {
  __shared__ int s[256];
  int tid = threadIdx.x, i = blockIdx.x * 256 + tid;
  int v = (i < N_NODES) ? deg[i] : 0;
  s[tid] = v;
  __syncthreads();
  for (int d = 1; d < 256; d <<= 1) {
    int t = (tid >= d) ? s[tid - d] : 0;
    __syncthreads();
    s[tid] += t;
    __syncthreads();
  }
  if (i < N_NODES) off[i] = s[tid] - v;
  if (tid == 255) bsum[blockIdx.x] = s[255];
}

__global__ __launch_bounds__(256) void scan2_kernel(int* __restrict__ bsum) {
  __shared__ int s[256];
  int tid = threadIdx.x;
  int v = (tid < NBLK) ? bsum[tid] : 0;
  s[tid] = v;
  __syncthreads();
  for (int d = 1; d < 256; d <<= 1) {
    int t = (tid >= d) ? s[tid - d] : 0;
    __syncthreads();
    s[tid] += t;
    __syncthreads();
  }
  if (tid < NBLK) bsum[tid] = s[tid] - v;
}

// scan finalize + cursor init + dis + packed {off,deg}
__global__ void scan3_kernel(int* __restrict__ off, const int* __restrict__ bsum,
                             int* __restrict__ cursor, const int* __restrict__ deg,
                             float* __restrict__ dis, int2* __restrict__ od) {
  int i = blockIdx.x * 256 + threadIdx.x;
  if (i < N_NODES) {
    int o = off[i] + bsum[blockIdx.x];
    off[i] = o;
    cursor[i] = o;
    int d = deg[i];
    dis[i] = d > 0 ? rsqrtf((float)d) : 0.f;
    int2 p; p.x = o; p.y = d;
    od[i] = p;
  }
}

// CSC scatter: perm + packed meta {row, nrm}
__global__ void scatter2_kernel(const int* __restrict__ rowI, const int* __restrict__ colI,
                                const float* __restrict__ dis, int* __restrict__ cursor,
                                int* __restrict__ perm, int2* __restrict__ metaP) {
  int e = blockIdx.x * blockDim.x + threadIdx.x;
  if (e < N_EDGES) {
    int c = colI[e], r = rowI[e];
    int p = atomicAdd(&cursor[c], 1);
    perm[p] = e;
    int2 m;
    m.x = r;
    m.y = __float_as_int(dis[r] * dis[c]);
    metaP[p] = m;
  }
}

// permute attr rows into CSC order, f32 -> bf16; 8 threads/row, 32B read / 16B write
__global__ void permA_kernel(const float* __restrict__ attr, const int* __restrict__ perm,
                             unsigned short* __restrict__ attrP) {
  int t = blockIdx.x * 256 + threadIdx.x;  // E*8 threads, 8 channels each
  int i = t >> 3, q = t & 7;
  if (i >= N_EDGES) return;
  int e = perm[i];
  float4 v0 = *(const float4*)(attr + (size_t)e * 64 + q * 8);
  float4 v1 = *(const float4*)(attr + (size_t)e * 64 + q * 8 + 4);
  u16x8 o;
  o[0] = f2bf(v0.x); o[1] = f2bf(v0.y); o[2] = f2bf(v0.z); o[3] = f2bf(v0.w);
  o[4] = f2bf(v1.x); o[5] = f2bf(v1.y); o[6] = f2bf(v1.z); o[7] = f2bf(v1.w);
  *(u16x8*)(attrP + (size_t)i * 64 + q * 8) = o;
}

// ---- MFMA node GEMM K=128 (layer 0): wave = 16 rows; bf16 out LINEAR ----
__global__ __launch_bounds__(256, 3) void node_mfma128_kernel(
    const float* __restrict__ X, const unsigned short* __restrict__ WT,
    const float* __restrict__ bP, unsigned short* __restrict__ Y) {
  const int lane = threadIdx.x & 63;
  const int lr = lane & 15, lg = lane >> 4;
  const int wt = (blockIdx.x * 256 + threadIdx.x) >> 6;
  if (wt * 16 >= N_NODES) return;
  const int rowbase = wt * 16;

  bf16x8 bfrag[4][4];
  float bias[4];
#pragma unroll
  for (int tn = 0; tn < 4; ++tn) {
    bias[tn] = bP[tn * 16 + lr];
#pragma unroll
    for (int ks = 0; ks < 4; ++ks)
      bfrag[tn][ks] = *(const bf16x8*)(WT + (tn * 16 + lr) * 128 + ks * 32 + lg * 8);
  }
  const float* xr = X + (size_t)(rowbase + lr) * 128;
  bf16x8 af[4];
#pragma unroll
  for (int ks = 0; ks < 4; ++ks) {
    float4 a = *(const float4*)(xr + ks * 32 + lg * 8);
    float4 b = *(const float4*)(xr + ks * 32 + lg * 8 + 4);
    bf16x8 f;
    f[0] = (short)f2bf(a.x); f[1] = (short)f2bf(a.y);
    f[2] = (short)f2bf(a.z); f[3] = (short)f2bf(a.w);
    f[4] = (short)f2bf(b.x); f[5] = (short)f2bf(b.y);
    f[6] = (short)f2bf(b.z); f[7] = (short)f2bf(b.w);
    af[ks] = f;
  }
  f32x4 acc[4];
#pragma unroll
  for (int tn = 0; tn < 4; ++tn) {
    f32x4 z = {bias[tn], bias[tn], bias[tn], bias[tn]};
#pragma unroll
    for (int ks = 0; ks < 4; ++ks)
      z = __builtin_amdgcn_mfma_f32_16x16x32_bf16(af[ks], bfrag[tn][ks], z, 0, 0, 0);
    acc[tn] = z;
  }
#pragma unroll
  for (int j = 0; j < 4; ++j) {
    ushort4 o = {f2bf(acc[0][j]), f2bf(acc[1][j]), f2bf(acc[2][j]), f2bf(acc[3][j])};
    *(ushort4*)(Y + (size_t)(rowbase + lg * 4 + j) * 64 + lr * 4) = o;
  }
}

// ---- MFMA node GEMM K=64 with fused input ReLU+LayerNorm ----
__global__ __launch_bounds__(256, 3) void node_mfma64_kernel(
    const float* __restrict__ X, const unsigned short* __restrict__ WT,
    const float* __restrict__ bP, const float* __restrict__ G,
    const float* __restrict__ BT, unsigned short* __restrict__ Y) {
  const int lane = threadIdx.x & 63;
  const int lr = lane & 15, lg = lane >> 4;
  const int wt = (blockIdx.x * 256 + threadIdx.x) >> 6;
  if (wt * 16 >= N_NODES) return;
  const int rowbase = wt * 16;

  bf16x8 bfrag[4][2];
  float bias[4];
#pragma unroll
  for (int tn = 0; tn < 4; ++tn) {
    bias[tn] = bP[tn * 16 + lr];
#pragma unroll
    for (int ks = 0; ks < 2; ++ks)
      bfrag[tn][ks] = *(const bf16x8*)(WT + (tn * 16 + lr) * 64 + ks * 32 + lg * 8);
  }
  const float* xr = X + (size_t)(rowbase + lr) * 64;
  float v[16];
#pragma unroll
  for (int ks = 0; ks < 2; ++ks) {
    float4 a = *(const float4*)(xr + ks * 32 + lg * 8);
    float4 b = *(const float4*)(xr + ks * 32 + lg * 8 + 4);
    v[ks * 8 + 0] = a.x; v[ks * 8 + 1] = a.y; v[ks * 8 + 2] = a.z; v[ks * 8 + 3] = a.w;
    v[ks * 8 + 4] = b.x; v[ks * 8 + 5] = b.y; v[ks * 8 + 6] = b.z; v[ks * 8 + 7] = b.w;
  }
  float s = 0.f;
#pragma unroll
  for (int i = 0; i < 16; ++i) { v[i] = fmaxf(v[i], 0.f); s += v[i]; }
  s += __shfl_xor(s, 16); s += __shfl_xor(s, 32);
  float mu = s * (1.f / 64.f);
  float q = 0.f;
#pragma unroll
  for (int i = 0; i < 16; ++i) { float d = v[i] - mu; q += d * d; }
  q += __shfl_xor(q, 16); q += __shfl_xor(q, 32);
  float is = rsqrtf(q * (1.f / 64.f) + LN_EPS);
  bf16x8 af[2];
#pragma unroll
  for (int ks = 0; ks < 2; ++ks) {
    const float* gp = G + ks * 32 + lg * 8;
    const float* bp = BT + ks * 32 + lg * 8;
    float4 g0 = *(const float4*)(gp), g1 = *(const float4*)(gp + 4);
    float4 t0 = *(const float4*)(bp), t1 = *(const float4*)(bp + 4);
    float gg[8] = {g0.x, g0.y, g0.z, g0.w, g1.x, g1.y, g1.z, g1.w};
    float tt[8] = {t0.x, t0.y, t0.z, t0.w, t1.x, t1.y, t1.z, t1.w};
    bf16x8 f;
#pragma unroll
    for (int i = 0; i < 8; ++i)
      f[i] = (short)f2bf((v[ks * 8 + i] - mu) * is * gg[i] + tt[i]);
    af[ks] = f;
  }
  f32x4 acc[4];
#pragma unroll
  for (int tn = 0; tn < 4; ++tn) {
    f32x4 z = {bias[tn], bias[tn], bias[tn], bias[tn]};
    z = __builtin_amdgcn_mfma_f32_16x16x32_bf16(af[0], bfrag[tn][0], z, 0, 0, 0);
    z = __builtin_amdgcn_mfma_f32_16x16x32_bf16(af[1], bfrag[tn][1], z, 0, 0, 0);
    acc[tn] = z;
  }
#pragma unroll
  for (int j = 0; j < 4; ++j) {
    ushort4 o = {f2bf(acc[0][j]), f2bf(acc[1][j]), f2bf(acc[2][j]), f2bf(acc[3][j])};
    *(ushort4*)(Y + (size_t)(rowbase + lg * 4 + j) * 64 + lr * 4) = o;
  }
}

// ---- per-destination fused edge GEMM + aggregation: 2 cols per wave,
//      software-interleaved independent load chains (round-11 proven) ----
__global__ __launch_bounds__(256, 3) void edge_agg_kernel(
    const unsigned short* __restrict__ attrP, const int2* __restrict__ metaP,
    const int2* __restrict__ od, const unsigned short* __restrict__ WcT,
    const float* __restrict__ bc, const unsigned short* __restrict__ XLb,
    float* __restrict__ OUT) {
  const int lane = threadIdx.x & 63;
  const int lr = lane & 15, lg = lane >> 4;
  const int gw = (blockIdx.x * 256 + threadIdx.x) >> 6;
  const int cA = gw * 2, cB = cA + 1;
  if (cA >= N_NODES) return;
  const bool hasB = cB < N_NODES;

  // start the longest chains first
  int2 oA = od[cA];
  int2 oB = hasB ? od[cB] : make_int2(0, 0);

  bf16x8 bfrag[4][2];
  float bias[4];
#pragma unroll
  for (int tn = 0; tn < 4; ++tn) {
    bias[tn] = bc[tn * 16 + lr];
#pragma unroll
    for (int kb = 0; kb < 2; ++kb)
      bfrag[tn][kb] = *(const bf16x8*)(WcT + (tn * 16 + lr) * 64 + kb * 32 + lg * 8);
  }

  const int nbA = (oA.y + 15) >> 4;
  const int nbB = (oB.y + 15) >> 4;
  const int nb = nbA > nbB ? nbA : nbB;
  const int lastA = oA.x + (oA.y > 0 ? oA.y - 1 : 0);
  const int lastB = oB.x + (oB.y > 0 ? oB.y - 1 : 0);
  float fsA[4] = {0.f, 0.f, 0.f, 0.f};
  float fsB[4] = {0.f, 0.f, 0.f, 0.f};

#pragma unroll 1
  for (int b = 0; b < nb; ++b) {
    const int base = b * 16;
    const bool actA = b < nbA, actB = b < nbB;  // wave-uniform
    bf16x8 a0A, a1A, a0B, a1B;
    float nmA[4], nmB[4];
    int rjA[4], rjB[4];
    ushort4 xqA[4], xqB[4];
    if (actA) {
      int ea = min(oA.x + base + lr, lastA);
      const unsigned short* ap = attrP + (size_t)ea * 64 + lg * 8;
      a0A = *(const bf16x8*)(ap);
      a1A = *(const bf16x8*)(ap + 32);
#pragma unroll
      for (int j = 0; j < 4; ++j) {
        int idx = base + lg * 4 + j;
        int2 m = metaP[min(oA.x + idx, lastA)];
        rjA[j] = m.x;
        nmA[j] = (idx < oA.y) ? __int_as_float(m.y) : 0.f;
      }
#pragma unroll
      for (int j = 0; j < 4; ++j)
        xqA[j] = *(const ushort4*)(XLb + (size_t)rjA[j] * 64 + lr * 4);
    }
    if (actB) {
      int ea = min(oB.x + base + lr, lastB);
      const unsigned short* ap = attrP + (size_t)ea * 64 + lg * 8;
      a0B = *(const bf16x8*)(ap);
      a1B = *(const bf16x8*)(ap + 32);
#pragma unroll
      for (int j = 0; j < 4; ++j) {
        int idx = base + lg * 4 + j;
        int2 m = metaP[min(oB.x + idx, lastB)];
        rjB[j] = m.x;
        nmB[j] = (idx < oB.y) ? __int_as_float(m.y) : 0.f;
      }
#pragma unroll
      for (int j = 0; j < 4; ++j)
        xqB[j] = *(const ushort4*)(XLb + (size_t)rjB[j] * 64 + lr * 4);
    }
    if (actA) {
      f32x4 acc[4];
#pragma unroll
      for (int tn = 0; tn < 4; ++tn) {
        f32x4 z = {bias[tn], bias[tn], bias[tn], bias[tn]};
        z = __builtin_amdgcn_mfma_f32_16x16x32_bf16(a0A, bfrag[tn][0], z, 0, 0, 0);
        z = __builtin_amdgcn_mfma_f32_16x16x32_bf16(a1A, bfrag[tn][1], z, 0, 0, 0);
        acc[tn] = z;
      }
#pragma unroll
      for (int j = 0; j < 4; ++j) {
        float x0 = bf2f(xqA[j].x), x1 = bf2f(xqA[j].y);
        float x2 = bf2f(xqA[j].z), x3 = bf2f(xqA[j].w);
        fsA[0] = fmaf(acc[0][j] * nmA[j], x0, fsA[0]);
        fsA[1] = fmaf(acc[1][j] * nmA[j], x1, fsA[1]);
        fsA[2] = fmaf(acc[2][j] * nmA[j], x2, fsA[2]);
        fsA[3] = fmaf(acc[3][j] * nmA[j], x3, fsA[3]);
      }
    }
    if (actB) {
      f32x4 acc[4];
#pragma unroll
      for (int tn = 0; tn < 4; ++tn) {
        f32x4 z = {bias[tn], bias[tn], bias[tn], bias[tn]};
        z = __builtin_amdgcn_mfma_f32_16x16x32_bf16(a0B, bfrag[tn][0], z, 0, 0, 0);
        z = __builtin_amdgcn_mfma_f32_16x16x32_bf16(a1B, bfrag[tn][1], z, 0, 0, 0);
        acc[tn] = z;
      }
#pragma unroll
      for (int j = 0; j < 4; ++j) {
        float x0 = bf2f(xqB[j].x), x1 = bf2f(xqB[j].y);
        float x2 = bf2f(xqB[j].z), x3 = bf2f(xqB[j].w);
        fsB[0] = fmaf(acc[0][j] * nmB[j], x0, fsB[0]);
        fsB[1] = fmaf(acc[1][j] * nmB[j], x1, fsB[1]);
        fsB[2] = fmaf(acc[2][j] * nmB[j], x2, fsB[2]);
        fsB[3] = fmaf(acc[3][j] * nmB[j], x3, fsB[3]);
      }
    }
  }
#pragma unroll
  for (int tn = 0; tn < 4; ++tn) {
    fsA[tn] += __shfl_xor(fsA[tn], 16);
    fsA[tn] += __shfl_xor(fsA[tn], 32);
    fsB[tn] += __shfl_xor(fsB[tn], 16);
    fsB[tn] += __shfl_xor(fsB[tn], 32);
  }
  if (lg == 0) {
    float4 oa = {fsA[0], fsA[1], fsA[2], fsA[3]};  // channels lr*4 .. lr*4+3
    *(float4*)(OUT + (size_t)cA * 64 + lr * 4) = oa;
    if (hasB) {
      float4 ob = {fsB[0], fsB[1], fsB[2], fsB[3]};
      *(float4*)(OUT + (size_t)cB * 64 + lr * 4) = ob;
    }
  }
}

extern "C" void kernel_launch(void* const* d_in, const int* in_sizes, int n_in,
                              void* d_out, int out_size, void* d_ws, size_t ws_size,
                              hipStream_t stream) {
  const float* x    = (const float*)d_in[0];
  const int* eidx   = (const int*)d_in[1];
  const float* attr = (const float*)d_in[2];
  const float* We  = (const float*)d_in[3];
  const float* be  = (const float*)d_in[4];
  const float* W0  = (const float*)d_in[5];  const float* b0  = (const float*)d_in[6];
  const float* eW0 = (const float*)d_in[7];  const float* eb0 = (const float*)d_in[8];
  const float* W1  = (const float*)d_in[9];  const float* b1  = (const float*)d_in[10];
  const float* eW1 = (const float*)d_in[11]; const float* eb1 = (const float*)d_in[12];
  const float* W2  = (const float*)d_in[13]; const float* b2  = (const float*)d_in[14];
  const float* eW2 = (const float*)d_in[15]; const float* eb2 = (const float*)d_in[16];
  const float* g0  = (const float*)d_in[17]; const float* bt0 = (const float*)d_in[18];
  const float* g1  = (const float*)d_in[19]; const float* bt1 = (const float*)d_in[20];
  const int* rowI = eidx;
  const int* colI = eidx + N_EDGES;

  char* base = (char*)d_ws;
  size_t pos = 0;
  auto alloc = [&](size_t b) -> char* {
    char* p = base + pos;
    pos += (b + 255) & ~(size_t)255;
    return p;
  };
  unsigned short* XLb = (unsigned short*)alloc((size_t)N_NODES * 64 * 2);
  float* hB   = (float*)alloc((size_t)N_NODES * 64 * 4);
  int2* metaP = (int2*)alloc((size_t)N_EDGES * 8);
  int* perm   = (int*)alloc((size_t)N_EDGES * 4);
  int* degI   = (int*)alloc((size_t)N_NODES * 4);
  float* disF = (float*)alloc((size_t)N_NODES * 4);
  int* offB   = (int*)alloc((size_t)N_NODES * 4);
  int* curB   = (int*)alloc((size_t)N_NODES * 4);
  int2* od    = (int2*)alloc((size_t)N_NODES * 8);
  int* bsum   = (int*)alloc(256 * 4);
  unsigned short* WcT = (unsigned short*)alloc(3 * 4096 * 2);
  float* bcC  = (float*)alloc(3 * 64 * 4);
  unsigned short* W0T = (unsigned short*)alloc(64 * 128 * 2);
  unsigned short* W1T = (unsigned short*)alloc(64 * 64 * 2);
  unsigned short* W2T = (unsigned short*)alloc(64 * 64 * 2);
  float* bPn  = (float*)alloc(3 * 64 * 4);
  unsigned short* attrP = (unsigned short*)alloc((size_t)N_EDGES * 64 * 2);
  (void)ws_size;
  float* out = (float*)d_out;

  // CSC build (sorted by destination col)
  hipMemsetAsync(degI, 0, (size_t)N_NODES * 4, stream);
  hist_kernel<<<N_EDGES / 256, 256, 0, stream>>>(colI, degI);
  scan1_kernel<<<NBLK, 256, 0, stream>>>(degI, offB, bsum);
  scan2_kernel<<<1, 256, 0, stream>>>(bsum);
  scan3_kernel<<<NBLK, 256, 0, stream>>>(offB, bsum, curB, degI, disF, od);
  scatter2_kernel<<<N_EDGES / 256, 256, 0, stream>>>(rowI, colI, disF, curB, perm, metaP);
  permA_kernel<<<(N_EDGES * 8) / 256, 256, 0, stream>>>(attr, perm, attrP);
  wcomb_kernel<<<3, 256, 0, stream>>>(We, be, eW0, eb0, eW1, eb1, eW2, eb2, WcT, bcC);
  wnode_kernel<<<3, 256, 0, stream>>>(W0, b0, W1, b1, W2, b2, W0T, W1T, W2T, bPn);

  const int node_grid = (N_NODES / 16 + 3) / 4;  // 16 rows/wave, 4 waves/block
  const int agg_grid = (N_NODES + 7) / 8;        // 2 cols/wave, 4 waves/block
  // layer 0
  node_mfma128_kernel<<<node_grid, 256, 0, stream>>>(x, W0T, bPn, XLb);
  edge_agg_kernel<<<agg_grid, 256, 0, stream>>>(attrP, metaP, od, WcT, bcC, XLb, hB);
  // layer 1 (input ReLU+LN fused)
  node_mfma64_kernel<<<node_grid, 256, 0, stream>>>(hB, W1T, bPn + 64, g0, bt0, XLb);
  edge_agg_kernel<<<agg_grid, 256, 0, stream>>>(attrP, metaP, od, WcT + 4096, bcC + 64, XLb, hB);
  // layer 2
  node_mfma64_kernel<<<node_grid, 256, 0, stream>>>(hB, W2T, bPn + 128, g1, bt1, XLb);
  edge_agg_kernel<<<agg_grid, 256, 0, stream>>>(attrP, metaP, od, WcT + 8192, bcC + 128, XLb, out);
}

// Round 14
// 395.506 us; speedup vs baseline: 1.8177x; 1.1625x over previous
//
#include <hip/hip_runtime.h>

#define N_NODES 50000
#define N_EDGES 800000
#define LN_EPS 1e-5f
#define NBLK 196  // ceil(N_NODES/256)

typedef __attribute__((ext_vector_type(8))) short bf16x8;
typedef __attribute__((ext_vector_type(8))) unsigned short u16x8;
typedef __attribute__((ext_vector_type(4))) float f32x4;

static __device__ inline unsigned short f2bf(float f) {
  unsigned u = __float_as_uint(f);
  unsigned r = ((u >> 16) & 1) + 0x7fffu;
  return (unsigned short)((u + r) >> 16);
}
static __device__ inline float bf2f(unsigned short u) {
  return __uint_as_float((unsigned)u << 16);
}

// Fragment n-index -> true channel permutation: p(n) = (n&15)*4 + (n>>4).
// Lane (lr,tn) owns true channels lr*4+tn (contiguous), so bf16 node-feature
// buffers stay LINEAR; MFMA D rows are lg*4+j.

// ---- combined edge transforms, PARALLEL: 48 blocks = 3 layers x 16 slices ----
// WcT[L][n][k] = (We@eW)[k][p(n)] bf16, bcC[L][n] = bias[p(n)]
__global__ void wcomb_kernel(const float* __restrict__ We, const float* __restrict__ be,
                             const float* __restrict__ eW0, const float* __restrict__ eb0,
                             const float* __restrict__ eW1, const float* __restrict__ eb1,
                             const float* __restrict__ eW2, const float* __restrict__ eb2,
                             unsigned short* __restrict__ WcT, float* __restrict__ bcC) {
  int L = blockIdx.x >> 4, slice = blockIdx.x & 15;
  const float* eW = L == 0 ? eW0 : (L == 1 ? eW1 : eW2);
  const float* eb = L == 0 ? eb0 : (L == 1 ? eb1 : eb2);
  int tid = threadIdx.x;
  int idx = slice * 256 + tid;           // 0..4095; wave has uniform k, lane = n
  int k = idx >> 6, n = idx & 63;
  int ch = (n & 15) * 4 + (n >> 4);      // p(n)
  float s = 0.f;
#pragma unroll 8
  for (int j = 0; j < 64; ++j) s = fmaf(We[k * 64 + j], eW[j * 64 + ch], s);
  WcT[L * 4096 + n * 64 + k] = f2bf(s);
  if (slice == 0 && tid < 64) {
    int c2 = (tid & 15) * 4 + (tid >> 4);
    float b = eb[c2];
#pragma unroll 8
    for (int j = 0; j < 64; ++j) b = fmaf(be[j], eW[j * 64 + c2], b);
    bcC[L * 64 + tid] = b;
  }
}

// ---- node weight prep, PARALLEL: 96 blocks = 3 layers x 32 slices ----
// WT[n][k] = W[k][p(n)] bf16, bP[n] = b[p(n)]
__global__ void wnode_kernel(const float* __restrict__ W0, const float* __restrict__ b0,
                             const float* __restrict__ W1, const float* __restrict__ b1,
                             const float* __restrict__ W2, const float* __restrict__ b2,
                             unsigned short* __restrict__ W0T, unsigned short* __restrict__ W1T,
                             unsigned short* __restrict__ W2T, float* __restrict__ bP) {
  int L = blockIdx.x >> 5, slice = blockIdx.x & 31;
  const float* W = L == 0 ? W0 : (L == 1 ? W1 : W2);
  const float* b = L == 0 ? b0 : (L == 1 ? b1 : b2);
  unsigned short* WT = L == 0 ? W0T : (L == 1 ? W1T : W2T);
  const int K = L == 0 ? 128 : 64;
  int tid = threadIdx.x;
  int idx = slice * 256 + tid;
  if (idx < 64 * K) {
    int n = idx / K, k = idx % K;
    int ch = (n & 15) * 4 + (n >> 4);
    WT[idx] = f2bf(W[k * 64 + ch]);
  }
  if (slice == 0 && tid < 64) {
    int ch = (tid & 15) * 4 + (tid >> 4);
    bP[L * 64 + tid] = b[ch];
  }
}

// ---- CSC build ----
__global__ void hist_kernel(const int* __restrict__ col, int* __restrict__ deg) {
  int e = blockIdx.x * blockDim.x + threadIdx.x;
  if (e < N_EDGES) atomicAdd(&deg[col[e]], 1);
}

__global__ __launch_bounds__(256) void scan1_kernel(const int* __restrict__ deg,
                                                    int* __restrict__ off, int* __restrict__ bsum) {
  __shared__ int s[256];
  int tid = threadIdx.x, i = blockIdx.x * 256 + tid;
  int v = (i < N_NODES) ? deg[i] : 0;
  s[tid] = v;
  __syncthreads();
  for (int d = 1; d < 256; d <<= 1) {
    int t = (tid >= d) ? s[tid - d] : 0;
    __syncthreads();
    s[tid] += t;
    __syncthreads();
  }
  if (i < N_NODES) off[i] = s[tid] - v;
  if (tid == 255) bsum[blockIdx.x] = s[255];
}

__global__ __launch_bounds__(256) void scan2_kernel(int* __restrict__ bsum) {
  __shared__ int s[256];
  int tid = threadIdx.x;
  int v = (tid < NBLK) ? bsum[tid] : 0;
  s[tid] = v;
  __syncthreads();
  for (int d = 1; d < 256; d <<= 1) {
    int t = (tid >= d) ? s[tid - d] : 0;
    __syncthreads();
    s[tid] += t;
    __syncthreads();
  }
  if (tid < NBLK) bsum[tid] = s[tid] - v;
}

// scan finalize + cursor init + dis + packed {off,deg}
__global__ void scan3_kernel(int* __restrict__ off, const int* __restrict__ bsum,
                             int* __restrict__ cursor, const int* __restrict__ deg,
                             float* __restrict__ dis, int2* __restrict__ od) {
  int i = blockIdx.x * 256 + threadIdx.x;
  if (i < N_NODES) {
    int o = off[i] + bsum[blockIdx.x];
    off[i] = o;
    cursor[i] = o;
    int d = deg[i];
    dis[i] = d > 0 ? rsqrtf((float)d) : 0.f;
    int2 p; p.x = o; p.y = d;
    od[i] = p;
  }
}

// CSC scatter: perm + packed meta {row, nrm}
__global__ void scatter2_kernel(const int* __restrict__ rowI, const int* __restrict__ colI,
                                const float* __restrict__ dis, int* __restrict__ cursor,
                                int* __restrict__ perm, int2* __restrict__ metaP) {
  int e = blockIdx.x * blockDim.x + threadIdx.x;
  if (e < N_EDGES) {
    int c = colI[e], r = rowI[e];
    int p = atomicAdd(&cursor[c], 1);
    perm[p] = e;
    int2 m;
    m.x = r;
    m.y = __float_as_int(dis[r] * dis[c]);
    metaP[p] = m;
  }
}

// permute attr rows into CSC order, f32 -> bf16; 8 threads/row, 32B read / 16B write
__global__ void permA_kernel(const float* __restrict__ attr, const int* __restrict__ perm,
                             unsigned short* __restrict__ attrP) {
  int t = blockIdx.x * 256 + threadIdx.x;  // E*8 threads, 8 channels each
  int i = t >> 3, q = t & 7;
  if (i >= N_EDGES) return;
  int e = perm[i];
  float4 v0 = *(const float4*)(attr + (size_t)e * 64 + q * 8);
  float4 v1 = *(const float4*)(attr + (size_t)e * 64 + q * 8 + 4);
  u16x8 o;
  o[0] = f2bf(v0.x); o[1] = f2bf(v0.y); o[2] = f2bf(v0.z); o[3] = f2bf(v0.w);
  o[4] = f2bf(v1.x); o[5] = f2bf(v1.y); o[6] = f2bf(v1.z); o[7] = f2bf(v1.w);
  *(u16x8*)(attrP + (size_t)i * 64 + q * 8) = o;
}

// ---- MFMA node GEMM K=128 (layer 0): wave = 16 rows; bf16 out LINEAR ----
__global__ __launch_bounds__(256, 3) void node_mfma128_kernel(
    const float* __restrict__ X, const unsigned short* __restrict__ WT,
    const float* __restrict__ bP, unsigned short* __restrict__ Y) {
  const int lane = threadIdx.x & 63;
  const int lr = lane & 15, lg = lane >> 4;
  const int wt = (blockIdx.x * 256 + threadIdx.x) >> 6;
  if (wt * 16 >= N_NODES) return;
  const int rowbase = wt * 16;

  bf16x8 bfrag[4][4];
  float bias[4];
#pragma unroll
  for (int tn = 0; tn < 4; ++tn) {
    bias[tn] = bP[tn * 16 + lr];
#pragma unroll
    for (int ks = 0; ks < 4; ++ks)
      bfrag[tn][ks] = *(const bf16x8*)(WT + (tn * 16 + lr) * 128 + ks * 32 + lg * 8);
  }
  const float* xr = X + (size_t)(rowbase + lr) * 128;
  bf16x8 af[4];
#pragma unroll
  for (int ks = 0; ks < 4; ++ks) {
    float4 a = *(const float4*)(xr + ks * 32 + lg * 8);
    float4 b = *(const float4*)(xr + ks * 32 + lg * 8 + 4);
    bf16x8 f;
    f[0] = (short)f2bf(a.x); f[1] = (short)f2bf(a.y);
    f[2] = (short)f2bf(a.z); f[3] = (short)f2bf(a.w);
    f[4] = (short)f2bf(b.x); f[5] = (short)f2bf(b.y);
    f[6] = (short)f2bf(b.z); f[7] = (short)f2bf(b.w);
    af[ks] = f;
  }
  f32x4 acc[4];
#pragma unroll
  for (int tn = 0; tn < 4; ++tn) {
    f32x4 z = {bias[tn], bias[tn], bias[tn], bias[tn]};
#pragma unroll
    for (int ks = 0; ks < 4; ++ks)
      z = __builtin_amdgcn_mfma_f32_16x16x32_bf16(af[ks], bfrag[tn][ks], z, 0, 0, 0);
    acc[tn] = z;
  }
#pragma unroll
  for (int j = 0; j < 4; ++j) {
    ushort4 o = {f2bf(acc[0][j]), f2bf(acc[1][j]), f2bf(acc[2][j]), f2bf(acc[3][j])};
    *(ushort4*)(Y + (size_t)(rowbase + lg * 4 + j) * 64 + lr * 4) = o;
  }
}

// ---- MFMA node GEMM K=64 with fused input ReLU+LayerNorm ----
__global__ __launch_bounds__(256, 3) void node_mfma64_kernel(
    const float* __restrict__ X, const unsigned short* __restrict__ WT,
    const float* __restrict__ bP, const float* __restrict__ G,
    const float* __restrict__ BT, unsigned short* __restrict__ Y) {
  const int lane = threadIdx.x & 63;
  const int lr = lane & 15, lg = lane >> 4;
  const int wt = (blockIdx.x * 256 + threadIdx.x) >> 6;
  if (wt * 16 >= N_NODES) return;
  const int rowbase = wt * 16;

  bf16x8 bfrag[4][2];
  float bias[4];
#pragma unroll
  for (int tn = 0; tn < 4; ++tn) {
    bias[tn] = bP[tn * 16 + lr];
#pragma unroll
    for (int ks = 0; ks < 2; ++ks)
      bfrag[tn][ks] = *(const bf16x8*)(WT + (tn * 16 + lr) * 64 + ks * 32 + lg * 8);
  }
  const float* xr = X + (size_t)(rowbase + lr) * 64;
  float v[16];
#pragma unroll
  for (int ks = 0; ks < 2; ++ks) {
    float4 a = *(const float4*)(xr + ks * 32 + lg * 8);
    float4 b = *(const float4*)(xr + ks * 32 + lg * 8 + 4);
    v[ks * 8 + 0] = a.x; v[ks * 8 + 1] = a.y; v[ks * 8 + 2] = a.z; v[ks * 8 + 3] = a.w;
    v[ks * 8 + 4] = b.x; v[ks * 8 + 5] = b.y; v[ks * 8 + 6] = b.z; v[ks * 8 + 7] = b.w;
  }
  float s = 0.f;
#pragma unroll
  for (int i = 0; i < 16; ++i) { v[i] = fmaxf(v[i], 0.f); s += v[i]; }
  s += __shfl_xor(s, 16); s += __shfl_xor(s, 32);
  float mu = s * (1.f / 64.f);
  float q = 0.f;
#pragma unroll
  for (int i = 0; i < 16; ++i) { float d = v[i] - mu; q += d * d; }
  q += __shfl_xor(q, 16); q += __shfl_xor(q, 32);
  float is = rsqrtf(q * (1.f / 64.f) + LN_EPS);
  bf16x8 af[2];
#pragma unroll
  for (int ks = 0; ks < 2; ++ks) {
    const float* gp = G + ks * 32 + lg * 8;
    const float* bp = BT + ks * 32 + lg * 8;
    float4 g0 = *(const float4*)(gp), g1 = *(const float4*)(gp + 4);
    float4 t0 = *(const float4*)(bp), t1 = *(const float4*)(bp + 4);
    float gg[8] = {g0.x, g0.y, g0.z, g0.w, g1.x, g1.y, g1.z, g1.w};
    float tt[8] = {t0.x, t0.y, t0.z, t0.w, t1.x, t1.y, t1.z, t1.w};
    bf16x8 f;
#pragma unroll
    for (int i = 0; i < 8; ++i)
      f[i] = (short)f2bf((v[ks * 8 + i] - mu) * is * gg[i] + tt[i]);
    af[ks] = f;
  }
  f32x4 acc[4];
#pragma unroll
  for (int tn = 0; tn < 4; ++tn) {
    f32x4 z = {bias[tn], bias[tn], bias[tn], bias[tn]};
    z = __builtin_amdgcn_mfma_f32_16x16x32_bf16(af[0], bfrag[tn][0], z, 0, 0, 0);
    z = __builtin_amdgcn_mfma_f32_16x16x32_bf16(af[1], bfrag[tn][1], z, 0, 0, 0);
    acc[tn] = z;
  }
#pragma unroll
  for (int j = 0; j < 4; ++j) {
    ushort4 o = {f2bf(acc[0][j]), f2bf(acc[1][j]), f2bf(acc[2][j]), f2bf(acc[3][j])};
    *(ushort4*)(Y + (size_t)(rowbase + lg * 4 + j) * 64 + lr * 4) = o;
  }
}

// ---- per-destination fused edge GEMM + aggregation: 2 cols per wave,
//      software-interleaved independent load chains (round-11/13 proven) ----
__global__ __launch_bounds__(256, 3) void edge_agg_kernel(
    const unsigned short* __restrict__ attrP, const int2* __restrict__ metaP,
    const int2* __restrict__ od, const unsigned short* __restrict__ WcT,
    const float* __restrict__ bc, const unsigned short* __restrict__ XLb,
    float* __restrict__ OUT) {
  const int lane = threadIdx.x & 63;
  const int lr = lane & 15, lg = lane >> 4;
  const int gw = (blockIdx.x * 256 + threadIdx.x) >> 6;
  const int cA = gw * 2, cB = cA + 1;
  if (cA >= N_NODES) return;
  const bool hasB = cB < N_NODES;

  // start the longest chains first
  int2 oA = od[cA];
  int2 oB = hasB ? od[cB] : make_int2(0, 0);

  bf16x8 bfrag[4][2];
  float bias[4];
#pragma unroll
  for (int tn = 0; tn < 4; ++tn) {
    bias[tn] = bc[tn * 16 + lr];
#pragma unroll
    for (int kb = 0; kb < 2; ++kb)
      bfrag[tn][kb] = *(const bf16x8*)(WcT + (tn * 16 + lr) * 64 + kb * 32 + lg * 8);
  }

  const int nbA = (oA.y + 15) >> 4;
  const int nbB = (oB.y + 15) >> 4;
  const int nb = nbA > nbB ? nbA : nbB;
  const int lastA = oA.x + (oA.y > 0 ? oA.y - 1 : 0);
  const int lastB = oB.x + (oB.y > 0 ? oB.y - 1 : 0);
  float fsA[4] = {0.f, 0.f, 0.f, 0.f};
  float fsB[4] = {0.f, 0.f, 0.f, 0.f};

#pragma unroll 1
  for (int b = 0; b < nb; ++b) {
    const int base = b * 16;
    const bool actA = b < nbA, actB = b < nbB;  // wave-uniform
    bf16x8 a0A, a1A, a0B, a1B;
    float nmA[4], nmB[4];
    int rjA[4], rjB[4];
    ushort4 xqA[4], xqB[4];
    if (actA) {
      int ea = min(oA.x + base + lr, lastA);
      const unsigned short* ap = attrP + (size_t)ea * 64 + lg * 8;
      a0A = *(const bf16x8*)(ap);
      a1A = *(const bf16x8*)(ap + 32);
#pragma unroll
      for (int j = 0; j < 4; ++j) {
        int idx = base + lg * 4 + j;
        int2 m = metaP[min(oA.x + idx, lastA)];
        rjA[j] = m.x;
        nmA[j] = (idx < oA.y) ? __int_as_float(m.y) : 0.f;
      }
#pragma unroll
      for (int j = 0; j < 4; ++j)
        xqA[j] = *(const ushort4*)(XLb + (size_t)rjA[j] * 64 + lr * 4);
    }
    if (actB) {
      int ea = min(oB.x + base + lr, lastB);
      const unsigned short* ap = attrP + (size_t)ea * 64 + lg * 8;
      a0B = *(const bf16x8*)(ap);
      a1B = *(const bf16x8*)(ap + 32);
#pragma unroll
      for (int j = 0; j < 4; ++j) {
        int idx = base + lg * 4 + j;
        int2 m = metaP[min(oB.x + idx, lastB)];
        rjB[j] = m.x;
        nmB[j] = (idx < oB.y) ? __int_as_float(m.y) : 0.f;
      }
#pragma unroll
      for (int j = 0; j < 4; ++j)
        xqB[j] = *(const ushort4*)(XLb + (size_t)rjB[j] * 64 + lr * 4);
    }
    if (actA) {
      f32x4 acc[4];
#pragma unroll
      for (int tn = 0; tn < 4; ++tn) {
        f32x4 z = {bias[tn], bias[tn], bias[tn], bias[tn]};
        z = __builtin_amdgcn_mfma_f32_16x16x32_bf16(a0A, bfrag[tn][0], z, 0, 0, 0);
        z = __builtin_amdgcn_mfma_f32_16x16x32_bf16(a1A, bfrag[tn][1], z, 0, 0, 0);
        acc[tn] = z;
      }
#pragma unroll
      for (int j = 0; j < 4; ++j) {
        float x0 = bf2f(xqA[j].x), x1 = bf2f(xqA[j].y);
        float x2 = bf2f(xqA[j].z), x3 = bf2f(xqA[j].w);
        fsA[0] = fmaf(acc[0][j] * nmA[j], x0, fsA[0]);
        fsA[1] = fmaf(acc[1][j] * nmA[j], x1, fsA[1]);
        fsA[2] = fmaf(acc[2][j] * nmA[j], x2, fsA[2]);
        fsA[3] = fmaf(acc[3][j] * nmA[j], x3, fsA[3]);
      }
    }
    if (actB) {
      f32x4 acc[4];
#pragma unroll
      for (int tn = 0; tn < 4; ++tn) {
        f32x4 z = {bias[tn], bias[tn], bias[tn], bias[tn]};
        z = __builtin_amdgcn_mfma_f32_16x16x32_bf16(a0B, bfrag[tn][0], z, 0, 0, 0);
        z = __builtin_amdgcn_mfma_f32_16x16x32_bf16(a1B, bfrag[tn][1], z, 0, 0, 0);
        acc[tn] = z;
      }
#pragma unroll
      for (int j = 0; j < 4; ++j) {
        float x0 = bf2f(xqB[j].x), x1 = bf2f(xqB[j].y);
        float x2 = bf2f(xqB[j].z), x3 = bf2f(xqB[j].w);
        fsB[0] = fmaf(acc[0][j] * nmB[j], x0, fsB[0]);
        fsB[1] = fmaf(acc[1][j] * nmB[j], x1, fsB[1]);
        fsB[2] = fmaf(acc[2][j] * nmB[j], x2, fsB[2]);
        fsB[3] = fmaf(acc[3][j] * nmB[j], x3, fsB[3]);
      }
    }
  }
#pragma unroll
  for (int tn = 0; tn < 4; ++tn) {
    fsA[tn] += __shfl_xor(fsA[tn], 16);
    fsA[tn] += __shfl_xor(fsA[tn], 32);
    fsB[tn] += __shfl_xor(fsB[tn], 16);
    fsB[tn] += __shfl_xor(fsB[tn], 32);
  }
  if (lg == 0) {
    float4 oa = {fsA[0], fsA[1], fsA[2], fsA[3]};  // channels lr*4 .. lr*4+3
    *(float4*)(OUT + (size_t)cA * 64 + lr * 4) = oa;
    if (hasB) {
      float4 ob = {fsB[0], fsB[1], fsB[2], fsB[3]};
      *(float4*)(OUT + (size_t)cB * 64 + lr * 4) = ob;
    }
  }
}

extern "C" void kernel_launch(void* const* d_in, const int* in_sizes, int n_in,
                              void* d_out, int out_size, void* d_ws, size_t ws_size,
                              hipStream_t stream) {
  const float* x    = (const float*)d_in[0];
  const int* eidx   = (const int*)d_in[1];
  const float* attr = (const float*)d_in[2];
  const float* We  = (const float*)d_in[3];
  const float* be  = (const float*)d_in[4];
  const float* W0  = (const float*)d_in[5];  const float* b0  = (const float*)d_in[6];
  const float* eW0 = (const float*)d_in[7];  const float* eb0 = (const float*)d_in[8];
  const float* W1  = (const float*)d_in[9];  const float* b1  = (const float*)d_in[10];
  const float* eW1 = (const float*)d_in[11]; const float* eb1 = (const float*)d_in[12];
  const float* W2  = (const float*)d_in[13]; const float* b2  = (const float*)d_in[14];
  const float* eW2 = (const float*)d_in[15]; const float* eb2 = (const float*)d_in[16];
  const float* g0  = (const float*)d_in[17]; const float* bt0 = (const float*)d_in[18];
  const float* g1  = (const float*)d_in[19]; const float* bt1 = (const float*)d_in[20];
  const int* rowI = eidx;
  const int* colI = eidx + N_EDGES;

  char* base = (char*)d_ws;
  size_t pos = 0;
  auto alloc = [&](size_t b) -> char* {
    char* p = base + pos;
    pos += (b + 255) & ~(size_t)255;
    return p;
  };
  unsigned short* XLb = (unsigned short*)alloc((size_t)N_NODES * 64 * 2);
  float* hB   = (float*)alloc((size_t)N_NODES * 64 * 4);
  int2* metaP = (int2*)alloc((size_t)N_EDGES * 8);
  int* perm   = (int*)alloc((size_t)N_EDGES * 4);
  int* degI   = (int*)alloc((size_t)N_NODES * 4);
  float* disF = (float*)alloc((size_t)N_NODES * 4);
  int* offB   = (int*)alloc((size_t)N_NODES * 4);
  int* curB   = (int*)alloc((size_t)N_NODES * 4);
  int2* od    = (int2*)alloc((size_t)N_NODES * 8);
  int* bsum   = (int*)alloc(256 * 4);
  unsigned short* WcT = (unsigned short*)alloc(3 * 4096 * 2);
  float* bcC  = (float*)alloc(3 * 64 * 4);
  unsigned short* W0T = (unsigned short*)alloc(64 * 128 * 2);
  unsigned short* W1T = (unsigned short*)alloc(64 * 64 * 2);
  unsigned short* W2T = (unsigned short*)alloc(64 * 64 * 2);
  float* bPn  = (float*)alloc(3 * 64 * 4);
  unsigned short* attrP = (unsigned short*)alloc((size_t)N_EDGES * 64 * 2);
  (void)ws_size;
  float* out = (float*)d_out;

  // CSC build (sorted by destination col)
  hipMemsetAsync(degI, 0, (size_t)N_NODES * 4, stream);
  hist_kernel<<<N_EDGES / 256, 256, 0, stream>>>(colI, degI);
  scan1_kernel<<<NBLK, 256, 0, stream>>>(degI, offB, bsum);
  scan2_kernel<<<1, 256, 0, stream>>>(bsum);
  scan3_kernel<<<NBLK, 256, 0, stream>>>(offB, bsum, curB, degI, disF, od);
  scatter2_kernel<<<N_EDGES / 256, 256, 0, stream>>>(rowI, colI, disF, curB, perm, metaP);
  permA_kernel<<<(N_EDGES * 8) / 256, 256, 0, stream>>>(attr, perm, attrP);
  wcomb_kernel<<<48, 256, 0, stream>>>(We, be, eW0, eb0, eW1, eb1, eW2, eb2, WcT, bcC);
  wnode_kernel<<<96, 256, 0, stream>>>(W0, b0, W1, b1, W2, b2, W0T, W1T, W2T, bPn);

  const int node_grid = (N_NODES / 16 + 3) / 4;  // 16 rows/wave, 4 waves/block
  const int agg_grid = (N_NODES + 7) / 8;        // 2 cols/wave, 4 waves/block
  // layer 0
  node_mfma128_kernel<<<node_grid, 256, 0, stream>>>(x, W0T, bPn, XLb);
  edge_agg_kernel<<<agg_grid, 256, 0, stream>>>(attrP, metaP, od, WcT, bcC, XLb, hB);
  // layer 1 (input ReLU+LN fused)
  node_mfma64_kernel<<<node_grid, 256, 0, stream>>>(hB, W1T, bPn + 64, g0, bt0, XLb);
  edge_agg_kernel<<<agg_grid, 256, 0, stream>>>(attrP, metaP, od, WcT + 4096, bcC + 64, XLb, hB);
  // layer 2
  node_mfma64_kernel<<<node_grid, 256, 0, stream>>>(hB, W2T, bPn + 128, g1, bt1, XLb);
  edge_agg_kernel<<<agg_grid, 256, 0, stream>>>(attrP, metaP, od, WcT + 8192, bcC + 128, XLb, out);
}